// Round 6
// baseline (209.375 us; speedup 1.0000x reference)
//
#include <hip/hip_runtime.h>

// mixture/target/noise: (N, 2, C, T, F) float32
#define Nn 4
#define Cc 8
#define Tt 256
#define Ff 513
#define TFs (Tt * Ff)      // 131328
#define NCHUNK 64
#define TCHUNK (Tt / NCHUNK)            // 4 t-steps per wave
#define ACC_FLOATS ((size_t)2 * Nn * 72 * Ff)   // 295488 floats = 1.18 MB

// ---------------------------------------------------------------------------
// Stage 1: covariance accumulation, beamform-shaped.
// One WAVE per (f-slot, n, inp, chunk): 4608 independent 64-thread blocks,
// each doing 4 x (16-load burst -> 144 FMA) then 64 COALESCED atomicAdds into
// a 1.18 MB accumulator [inp][n][72][F] (comp-major: lane index = f, so each
// atomic instruction hits 64 consecutive addresses). No LDS, no barriers, no
// partial-buffer round-trip (was 38 MB); accumulator is LLC-resident.
// Every HBM input element is read exactly once. Previous designs (long waves,
// short bursts, barriers) all plateaued at ~2 TB/s read rate; this shape
// matches the measured-fast patterns (fill 6.6 TB/s, float4-copy 6.3 TB/s):
// many short waves, max outstanding loads, zero sync.
// ---------------------------------------------------------------------------
__global__ __launch_bounds__(64, 4) void cov_partial(
    const float* __restrict__ target, const float* __restrict__ noise,
    float* __restrict__ accum)
{
    int lane = threadIdx.x;
    int f = blockIdx.x * 64 + lane;       // 9 f-slots
    bool valid = f < Ff;
    int fc = valid ? f : (Ff - 1);        // clamp loads; mask atomics
    int n = blockIdx.y;
    int z = blockIdx.z;                   // z = chunk*2 + inp
    int inp = z & 1;
    int chunk = z >> 1;

    const float* src = inp ? noise : target;
    const float* bt = src + (size_t)n * 2 * Cc * TFs
                      + (size_t)(chunk * TCHUNK) * Ff + fc;

    float ar[36], ai[36];
#pragma unroll
    for (int p = 0; p < 36; ++p) { ar[p] = 0.f; ai[p] = 0.f; }

#pragma unroll 2
    for (int tt = 0; tt < TCHUNK; ++tt) {
        float re[8], im[8];
#pragma unroll
        for (int c = 0; c < 8; ++c) {
            re[c] = bt[(size_t)c * TFs];
            im[c] = bt[(size_t)(Cc + c) * TFs];
        }
        int p = 0;
#pragma unroll
        for (int a = 0; a < 8; ++a) {
#pragma unroll
            for (int b = a; b < 8; ++b, ++p) {
                ar[p] += re[a] * re[b] + im[a] * im[b];
                if (a != b)                       // diagonal imag is exactly 0
                    ai[p] += im[a] * re[b] - re[a] * im[b];
            }
        }
        bt += Ff;
    }

    if (valid) {
        float* dst = accum + ((size_t)inp * Nn + n) * (72 * (size_t)Ff) + f;
        int p = 0;
#pragma unroll
        for (int a = 0; a < 8; ++a) {
#pragma unroll
            for (int b = a; b < 8; ++b, ++p) {
                atomicAdd(dst + (size_t)(2 * p) * Ff, ar[p]);
                if (a != b)
                    atomicAdd(dst + (size_t)(2 * p + 1) * Ff, ai[p]);
                // diagonal imag: accumulator stays 0 from the memset
            }
        }
    }
}

// ---------------------------------------------------------------------------
// Stage 2: wave-parallel MVDR solve. ONE wave per (n,f). Lane (r,c) = entry
// (r,c); 4 scalar loads from the LLC-resident 1.18 MB accumulator (no reduce
// loop anymore). Gauss-Jordan with partial pivoting on [phiN | phiT] -> B
// ends as G = phiN^{-1} phiT; all cross-lane traffic via shuffles, zero
// barriers.
// ---------------------------------------------------------------------------
__global__ __launch_bounds__(64) void mvdr_weights(
    const float* __restrict__ accum, const int* __restrict__ ref_ptr,
    float2* __restrict__ wconj)
{
    int f = blockIdx.x;
    int n = blockIdx.y;
    int lane = threadIdx.x;

    int r = lane >> 3, c = lane & 7;
    int lo = r < c ? r : c, hi = r < c ? c : r;
    int p = lo * 8 - lo * (lo - 1) / 2 + (hi - lo);

    const float* PT = accum + ((size_t)0 * Nn + n) * (72 * (size_t)Ff) + f;
    const float* PN = accum + ((size_t)1 * Nn + n) * (72 * (size_t)Ff) + f;
    float sTx = PT[(size_t)(2 * p) * Ff], sTy = PT[(size_t)(2 * p + 1) * Ff];
    float sNx = PN[(size_t)(2 * p) * Ff], sNy = PN[(size_t)(2 * p + 1) * Ff];

    const float invT = 1.0f / (float)Tt;
    const float dl = 0.001f / 1.41421356237309515f;   // 0.001/sqrt(2)
    float sgn = (r > c) ? -1.f : 1.f;                 // Hermitian reconstruction

    float2 a = make_float2(sNx * invT, sgn * sNy * invT);
    float2 b = make_float2(sTx * invT, sgn * sTy * invT);
    if (r == c) { a.x += dl; a.y += dl; }             // complex diagonal loading

    for (int k = 0; k < 8; ++k) {
        // --- argmax |A_{jk}|^2 over j >= k (butterfly) ---
        float mag = (c == k && r >= k) ? (a.x * a.x + a.y * a.y) : -1.f;
        int midx = r;
#pragma unroll
        for (int st = 8; st < 64; st <<= 1) {
            float om = __shfl_xor(mag, st, 64);
            int   oi = __shfl_xor(midx, st, 64);
            if (om > mag) { mag = om; midx = oi; }
        }
        int piv = __shfl(midx, k, 64);

        // --- swap rows k <-> piv ---
        int srcr = (r == k) ? piv : ((r == piv) ? k : r);
        int src = srcr * 8 + c;
        a.x = __shfl(a.x, src, 64); a.y = __shfl(a.y, src, 64);
        b.x = __shfl(b.x, src, 64); b.y = __shfl(b.y, src, 64);

        // --- scale row k by 1/pivot ---
        float pvx = __shfl(a.x, k * 8 + k, 64), pvy = __shfl(a.y, k * 8 + k, 64);
        float d = pvx * pvx + pvy * pvy;
        float ipx = pvx / d, ipy = -pvy / d;
        if (r == k) {
            float2 t = a;
            a = make_float2(t.x * ipx - t.y * ipy, t.x * ipy + t.y * ipx);
            t = b;
            b = make_float2(t.x * ipx - t.y * ipy, t.x * ipy + t.y * ipx);
        }

        // --- eliminate all other rows ---
        float rax = __shfl(a.x, k * 8 + c, 64), ray = __shfl(a.y, k * 8 + c, 64);
        float rbx = __shfl(b.x, k * 8 + c, 64), rby = __shfl(b.y, k * 8 + c, 64);
        float fx  = __shfl(a.x, r * 8 + k, 64), fy  = __shfl(a.y, r * 8 + k, 64);
        if (r != k) {
            a.x -= fx * rax - fy * ray;  a.y -= fx * ray + fy * rax;
            b.x -= fx * rbx - fy * rby;  b.y -= fx * rby + fy * rbx;
        }
    }

    // --- l = trace(G): full-wave sum of diagonal entries of B ---
    float tx = (r == c) ? b.x : 0.f, ty = (r == c) ? b.y : 0.f;
#pragma unroll
    for (int st = 1; st < 64; st <<= 1) {
        tx += __shfl_xor(tx, st, 64);
        ty += __shfl_xor(ty, st, 64);
    }

    int ref = *ref_ptr;
    if (c == ref) {                                   // lane (r, ref) holds G_{r,ref}
        float den = tx * tx + ty * ty;
        float wx = (b.x * tx + b.y * ty) / den;       // W = G[:,ref] / l
        float wy = (b.y * tx - b.x * ty) / den;
        wconj[((size_t)n * Ff + f) * 8 + r] = make_float2(wx, -wy);  // conj(W)
    }
}

// ---------------------------------------------------------------------------
// Stage 3: X_bf(n,t,f) = sum_c conj(W)(n,f,c) * y(n,c,t,f)
// ---------------------------------------------------------------------------
__global__ __launch_bounds__(256) void beamform(
    const float* __restrict__ y, const float2* __restrict__ wconj,
    float* __restrict__ out)
{
    int idx = blockIdx.x * 256 + threadIdx.x;   // < N*T*F = 525312
    int n = idx / TFs;
    int rem = idx - n * TFs;
    int t = rem / Ff;
    int f = rem - t * Ff;

    size_t base_re = (size_t)n * 2 * Cc * TFs + (size_t)t * Ff + f;
    size_t base_im = base_re + (size_t)Cc * TFs;
    const float2* w = wconj + ((size_t)n * Ff + f) * 8;

    float xr = 0.f, xi = 0.f;
#pragma unroll
    for (int c = 0; c < Cc; ++c) {
        float yre = y[base_re + (size_t)c * TFs];
        float yim = y[base_im + (size_t)c * TFs];
        float2 wc = w[c];
        xr += wc.x * yre - wc.y * yim;
        xi += wc.x * yim + wc.y * yre;
    }
    size_t ob = (size_t)n * 2 * TFs + (size_t)t * Ff + f;
    out[ob] = xr;
    out[ob + TFs] = xi;
}

extern "C" void kernel_launch(void* const* d_in, const int* in_sizes, int n_in,
                              void* d_out, int out_size, void* d_ws, size_t ws_size,
                              hipStream_t stream) {
    const float* mixture = (const float*)d_in[0];
    const float* target  = (const float*)d_in[1];
    const float* noise   = (const float*)d_in[2];
    const int*   refp    = (const int*)d_in[3];
    float* out = (float*)d_out;

    float*  accum = (float*)d_ws;                       // 1.18 MB accumulator
    float2* wconj = (float2*)((char*)d_ws + (2 << 20)); // 131 KB at +2 MB

    hipMemsetAsync(accum, 0, ACC_FLOATS * sizeof(float), stream);
    cov_partial<<<dim3(9, Nn, NCHUNK * 2), 64, 0, stream>>>(target, noise, accum);
    mvdr_weights<<<dim3(Ff, Nn), 64, 0, stream>>>(accum, refp, wconj);
    beamform<<<dim3((Nn * TFs) / 256), 256, 0, stream>>>(mixture, wconj, out);
}

// Round 7
// 146.962 us; speedup vs baseline: 1.4247x; 1.4247x over previous
//
#include <hip/hip_runtime.h>

// mixture/target/noise: (N, 2, C, T, F) float32
#define Nn 4
#define Cc 8
#define Tt 256
#define Ff 513
#define TFs (Tt * Ff)      // 131328
#define NCHUNK 16
#define TCHUNK (Tt / NCHUNK)        // 16 t-steps per chunk, 4 per wave
#define SLAB ((size_t)Ff * 72)      // floats per (inp,n,chunk) slab

// ---------------------------------------------------------------------------
// Stage 1: partial covariances (R3 structure + register prefetch).
// 256-thread block = 4 waves; each wave accumulates 4 t-steps for the same
// 64-f range (every input element read exactly once). NEW: while computing
// t's 128 FMAs, the 16 loads of t+1 are already in flight (explicit register
// prefetch) -> the per-step s_waitcnt no longer exposes full HBM latency.
// Then 2-region LDS reduce (stride-73 rows: conflict-free) + one cooperative
// coalesced store. NOTE: input rows are 2052 B (=4 mod 16) -> vector loads
// along f are impossible by alignment; scalar coalesced 4 B lanes is optimal.
// Partial layout [inp][n][chunk][f][72]: 72 components of one f contiguous.
// ---------------------------------------------------------------------------
__global__ __launch_bounds__(256) void cov_partial(
    const float* __restrict__ target, const float* __restrict__ noise,
    float* __restrict__ partial)
{
    int tid = threadIdx.x;
    int lane = tid & 63, wave = tid >> 6;
    int f0 = blockIdx.x * 64;
    int f = f0 + lane;
    int fc = f < Ff ? f : (Ff - 1);        // clamp: no early return (barriers!)
    int n = blockIdx.y;
    int z = blockIdx.z;                    // z = chunk*2 + inp
    int inp = z & 1;
    int chunk = z >> 1;

    const float* src = inp ? noise : target;
    const float* bt = src + (size_t)n * 2 * Cc * TFs
                      + (size_t)(chunk * TCHUNK + wave * 4) * Ff + fc;

    float ar[36], ai[36];
#pragma unroll
    for (int p = 0; p < 36; ++p) { ar[p] = 0.f; ai[p] = 0.f; }

    float cre[8], cim[8];
#pragma unroll
    for (int c = 0; c < 8; ++c) {          // load t-step 0
        cre[c] = bt[(size_t)c * TFs];
        cim[c] = bt[(size_t)(Cc + c) * TFs];
    }

#pragma unroll
    for (int tt = 0; tt < 4; ++tt) {
        const float* nx = bt + Ff;
        float pre[8], pim[8];
        if (tt < 3) {                      // issue t+1's 16 loads BEFORE FMAs
#pragma unroll
            for (int c = 0; c < 8; ++c) {
                pre[c] = nx[(size_t)c * TFs];
                pim[c] = nx[(size_t)(Cc + c) * TFs];
            }
        }
        int p = 0;
#pragma unroll
        for (int a = 0; a < 8; ++a) {
#pragma unroll
            for (int b = a; b < 8; ++b, ++p) {
                ar[p] += cre[a] * cre[b] + cim[a] * cim[b];
                if (a != b)                // diagonal imag is exactly 0
                    ai[p] += cim[a] * cre[b] - cre[a] * cim[b];
            }
        }
        if (tt < 3) {
#pragma unroll
            for (int c = 0; c < 8; ++c) { cre[c] = pre[c]; cim[c] = pim[c]; }
        }
        bt = nx;
    }

    // --- 2-region LDS reduce across the 4 waves -----------------------------
    __shared__ float red[2][64][73];       // stride 73 -> conflict-free
    int reg = wave & 1;
    if (wave < 2) {
        int p = 0;
#pragma unroll
        for (int a = 0; a < 8; ++a)
#pragma unroll
            for (int b = a; b < 8; ++b, ++p) {
                red[reg][lane][2 * p]     = ar[p];
                red[reg][lane][2 * p + 1] = (a == b) ? 0.f : ai[p];
            }
    }
    __syncthreads();
    if (wave >= 2) {
        int p = 0;
#pragma unroll
        for (int a = 0; a < 8; ++a)
#pragma unroll
            for (int b = a; b < 8; ++b, ++p) {
                red[reg][lane][2 * p] += ar[p];
                if (a != b) red[reg][lane][2 * p + 1] += ai[p];
            }
    }
    __syncthreads();

    // --- cooperative coalesced store of the [64 f][72] slab -----------------
    int nf = Ff - f0; if (nf > 64) nf = 64;
    float* dst = partial + (((size_t)inp * Nn + n) * NCHUNK + chunk) * SLAB
                 + (size_t)f0 * 72;
    for (int i = tid; i < nf * 72; i += 256) {
        int fl = i / 72, j = i - fl * 72;
        dst[i] = red[0][fl][j] + red[1][fl][j];
    }
}

// ---------------------------------------------------------------------------
// Stage 2: chunk-reduce + wave-parallel MVDR solve. ONE wave per (n,f).
// Lane (r,c) = entry (r,c); lane float2-loads its pair from each 288 B slab
// window (coalesced). Gauss-Jordan with partial pivoting on [phiN | phiT] ->
// B = G = phiN^{-1} phiT; all cross-lane traffic via shuffles, zero barriers.
// NEW: wconj stored TRANSPOSED as [n][c][f] so beamform's per-channel reads
// are lane-contiguous (the old [n][f][c] layout made beamform do 64 B-stride
// gathers: 64 cachelines per load instruction -- R1's stage-2 pathology).
// ---------------------------------------------------------------------------
__global__ __launch_bounds__(64) void mvdr_weights(
    const float* __restrict__ partial, const int* __restrict__ ref_ptr,
    float2* __restrict__ wconj)
{
    int f = blockIdx.x;
    int n = blockIdx.y;
    int lane = threadIdx.x;

    int r = lane >> 3, c = lane & 7;
    int lo = r < c ? r : c, hi = r < c ? c : r;
    int p = lo * 8 - lo * (lo - 1) / 2 + (hi - lo);

    const float* pT = partial + ((size_t)(0 * Nn + n) * NCHUNK) * SLAB
                      + (size_t)f * 72 + 2 * p;
    const float* pN = partial + ((size_t)(1 * Nn + n) * NCHUNK) * SLAB
                      + (size_t)f * 72 + 2 * p;
    float2 sT = make_float2(0.f, 0.f), sN = make_float2(0.f, 0.f);
#pragma unroll
    for (int ch = 0; ch < NCHUNK; ++ch) {
        float2 vT = *(const float2*)(pT + ch * SLAB);
        float2 vN = *(const float2*)(pN + ch * SLAB);
        sT.x += vT.x; sT.y += vT.y;
        sN.x += vN.x; sN.y += vN.y;
    }

    const float invT = 1.0f / (float)Tt;
    const float dl = 0.001f / 1.41421356237309515f;   // 0.001/sqrt(2)
    float sgn = (r > c) ? -1.f : 1.f;                 // Hermitian reconstruction

    float2 a = make_float2(sN.x * invT, sgn * sN.y * invT);
    float2 b = make_float2(sT.x * invT, sgn * sT.y * invT);
    if (r == c) { a.x += dl; a.y += dl; }             // complex diagonal loading

    for (int k = 0; k < 8; ++k) {
        // --- argmax |A_{jk}|^2 over j >= k (butterfly) ---
        float mag = (c == k && r >= k) ? (a.x * a.x + a.y * a.y) : -1.f;
        int midx = r;
#pragma unroll
        for (int st = 8; st < 64; st <<= 1) {
            float om = __shfl_xor(mag, st, 64);
            int   oi = __shfl_xor(midx, st, 64);
            if (om > mag) { mag = om; midx = oi; }
        }
        int piv = __shfl(midx, k, 64);

        // --- swap rows k <-> piv ---
        int srcr = (r == k) ? piv : ((r == piv) ? k : r);
        int src = srcr * 8 + c;
        a.x = __shfl(a.x, src, 64); a.y = __shfl(a.y, src, 64);
        b.x = __shfl(b.x, src, 64); b.y = __shfl(b.y, src, 64);

        // --- scale row k by 1/pivot ---
        float pvx = __shfl(a.x, k * 8 + k, 64), pvy = __shfl(a.y, k * 8 + k, 64);
        float d = pvx * pvx + pvy * pvy;
        float ipx = pvx / d, ipy = -pvy / d;
        if (r == k) {
            float2 t = a;
            a = make_float2(t.x * ipx - t.y * ipy, t.x * ipy + t.y * ipx);
            t = b;
            b = make_float2(t.x * ipx - t.y * ipy, t.x * ipy + t.y * ipx);
        }

        // --- eliminate all other rows ---
        float rax = __shfl(a.x, k * 8 + c, 64), ray = __shfl(a.y, k * 8 + c, 64);
        float rbx = __shfl(b.x, k * 8 + c, 64), rby = __shfl(b.y, k * 8 + c, 64);
        float fx  = __shfl(a.x, r * 8 + k, 64), fy  = __shfl(a.y, r * 8 + k, 64);
        if (r != k) {
            a.x -= fx * rax - fy * ray;  a.y -= fx * ray + fy * rax;
            b.x -= fx * rbx - fy * rby;  b.y -= fx * rby + fy * rbx;
        }
    }

    // --- l = trace(G): full-wave sum of diagonal entries of B ---
    float tx = (r == c) ? b.x : 0.f, ty = (r == c) ? b.y : 0.f;
#pragma unroll
    for (int st = 1; st < 64; st <<= 1) {
        tx += __shfl_xor(tx, st, 64);
        ty += __shfl_xor(ty, st, 64);
    }

    int ref = *ref_ptr;
    if (c == ref) {                                   // lane (r, ref) holds G_{r,ref}
        float den = tx * tx + ty * ty;
        float wx = (b.x * tx + b.y * ty) / den;       // W = G[:,ref] / l
        float wy = (b.y * tx - b.x * ty) / den;
        // TRANSPOSED layout: [n][c][f]
        wconj[((size_t)n * 8 + r) * Ff + f] = make_float2(wx, -wy);  // conj(W)
    }
}

// ---------------------------------------------------------------------------
// Stage 3: X_bf(n,t,f) = sum_c conj(W)(n,f,c) * y(n,c,t,f)
// wconj layout [n][c][f]: per-channel load is lane-contiguous (512 B/wave).
// ---------------------------------------------------------------------------
__global__ __launch_bounds__(256) void beamform(
    const float* __restrict__ y, const float2* __restrict__ wconj,
    float* __restrict__ out)
{
    int idx = blockIdx.x * 256 + threadIdx.x;   // < N*T*F = 525312
    int n = idx / TFs;
    int rem = idx - n * TFs;
    int t = rem / Ff;
    int f = rem - t * Ff;

    size_t base_re = (size_t)n * 2 * Cc * TFs + (size_t)t * Ff + f;
    size_t base_im = base_re + (size_t)Cc * TFs;
    const float2* w = wconj + (size_t)n * 8 * Ff + f;

    float xr = 0.f, xi = 0.f;
#pragma unroll
    for (int c = 0; c < Cc; ++c) {
        float yre = y[base_re + (size_t)c * TFs];
        float yim = y[base_im + (size_t)c * TFs];
        float2 wc = w[(size_t)c * Ff];
        xr += wc.x * yre - wc.y * yim;
        xi += wc.x * yim + wc.y * yre;
    }
    size_t ob = (size_t)n * 2 * TFs + (size_t)t * Ff + f;
    out[ob] = xr;
    out[ob + TFs] = xi;
}

extern "C" void kernel_launch(void* const* d_in, const int* in_sizes, int n_in,
                              void* d_out, int out_size, void* d_ws, size_t ws_size,
                              hipStream_t stream) {
    const float* mixture = (const float*)d_in[0];
    const float* target  = (const float*)d_in[1];
    const float* noise   = (const float*)d_in[2];
    const int*   refp    = (const int*)d_in[3];
    float* out = (float*)d_out;

    // partial: 2 * Nn * NCHUNK * Ff * 72 floats = ~18.9 MB (ws is ~256 MB)
    float*  partial = (float*)d_ws;
    float2* wconj = (float2*)((char*)d_ws +
                              (size_t)2 * Nn * NCHUNK * SLAB * sizeof(float));

    cov_partial<<<dim3(9, Nn, NCHUNK * 2), 256, 0, stream>>>(target, noise, partial);
    mvdr_weights<<<dim3(Ff, Nn), 64, 0, stream>>>(partial, refp, wconj);
    beamform<<<dim3((Nn * TFs) / 256), 256, 0, stream>>>(mixture, wconj, out);
}

// Round 8
// 141.540 us; speedup vs baseline: 1.4793x; 1.0383x over previous
//
#include <hip/hip_runtime.h>

// mixture/target/noise: (N, 2, C, T, F) float32
#define Nn 4
#define Cc 8
#define Tt 256
#define Ff 513
#define TFs (Tt * Ff)      // 131328
#define NCHUNK 16
#define TCHUNK (Tt / NCHUNK)        // 16 t-steps per chunk, 4 per wave
#define SLAB ((size_t)Ff * 72)      // floats per (inp,n,chunk) slab

// ---------------------------------------------------------------------------
// Stage 1: partial covariances (R3 structure + 2-t-step load batching).
// 256-thread block = 4 waves; each wave accumulates 4 t-steps for the same
// 64-f range (every input element read exactly once). The wave's 4 t-steps
// are processed as TWO batches of 32 back-to-back loads (t and t+1 together)
// -> 8 KB outstanding per wave, 128 KB per CU at 16 resident waves: double
// R3's load window, same 4-waves/SIMD VGPR class (72 acc + 32 loads ~119).
// Then 2-region LDS reduce (stride-73 rows: conflict-free) + one cooperative
// coalesced store. NOTE: input rows are 2052 B (=4 mod 16) -> vector loads
// along f are impossible by alignment; scalar coalesced 4 B lanes is optimal.
// Partial layout [inp][n][chunk][f][72]: 72 components of one f contiguous.
// ---------------------------------------------------------------------------
__global__ __launch_bounds__(256) void cov_partial(
    const float* __restrict__ target, const float* __restrict__ noise,
    float* __restrict__ partial)
{
    int tid = threadIdx.x;
    int lane = tid & 63, wave = tid >> 6;
    int f0 = blockIdx.x * 64;
    int f = f0 + lane;
    int fc = f < Ff ? f : (Ff - 1);        // clamp: no early return (barriers!)
    int n = blockIdx.y;
    int z = blockIdx.z;                    // z = chunk*2 + inp
    int inp = z & 1;
    int chunk = z >> 1;

    const float* src = inp ? noise : target;
    const float* bt = src + (size_t)n * 2 * Cc * TFs
                      + (size_t)(chunk * TCHUNK + wave * 4) * Ff + fc;

    float ar[36], ai[36];
#pragma unroll
    for (int p = 0; p < 36; ++p) { ar[p] = 0.f; ai[p] = 0.f; }

#pragma unroll
    for (int tp = 0; tp < 2; ++tp) {       // two t-pairs; 32 loads per batch
        float re0[8], im0[8], re1[8], im1[8];
#pragma unroll
        for (int c = 0; c < 8; ++c) {      // all 32 loads issued back-to-back
            re0[c] = bt[(size_t)c * TFs];
            im0[c] = bt[(size_t)(Cc + c) * TFs];
            re1[c] = bt[(size_t)c * TFs + Ff];
            im1[c] = bt[(size_t)(Cc + c) * TFs + Ff];
        }
        int p = 0;
#pragma unroll
        for (int a = 0; a < 8; ++a) {
#pragma unroll
            for (int b = a; b < 8; ++b, ++p) {
                ar[p] += re0[a] * re0[b] + im0[a] * im0[b];
                if (a != b)                // diagonal imag is exactly 0
                    ai[p] += im0[a] * re0[b] - re0[a] * im0[b];
            }
        }
        p = 0;
#pragma unroll
        for (int a = 0; a < 8; ++a) {
#pragma unroll
            for (int b = a; b < 8; ++b, ++p) {
                ar[p] += re1[a] * re1[b] + im1[a] * im1[b];
                if (a != b)
                    ai[p] += im1[a] * re1[b] - re1[a] * im1[b];
            }
        }
        bt += 2 * Ff;
    }

    // --- 2-region LDS reduce across the 4 waves -----------------------------
    __shared__ float red[2][64][73];       // stride 73 -> conflict-free
    int reg = wave & 1;
    if (wave < 2) {
        int p = 0;
#pragma unroll
        for (int a = 0; a < 8; ++a)
#pragma unroll
            for (int b = a; b < 8; ++b, ++p) {
                red[reg][lane][2 * p]     = ar[p];
                red[reg][lane][2 * p + 1] = (a == b) ? 0.f : ai[p];
            }
    }
    __syncthreads();
    if (wave >= 2) {
        int p = 0;
#pragma unroll
        for (int a = 0; a < 8; ++a)
#pragma unroll
            for (int b = a; b < 8; ++b, ++p) {
                red[reg][lane][2 * p] += ar[p];
                if (a != b) red[reg][lane][2 * p + 1] += ai[p];
            }
    }
    __syncthreads();

    // --- cooperative coalesced store of the [64 f][72] slab -----------------
    int nf = Ff - f0; if (nf > 64) nf = 64;
    float* dst = partial + (((size_t)inp * Nn + n) * NCHUNK + chunk) * SLAB
                 + (size_t)f0 * 72;
    for (int i = tid; i < nf * 72; i += 256) {
        int fl = i / 72, j = i - fl * 72;
        dst[i] = red[0][fl][j] + red[1][fl][j];
    }
}

// ---------------------------------------------------------------------------
// Stage 2: chunk-reduce + wave-parallel MVDR solve. ONE wave per (n,f).
// Lane (r,c) = entry (r,c); lane float2-loads its pair from each 288 B slab
// window (coalesced). Gauss-Jordan with partial pivoting on [phiN | phiT] ->
// B = G = phiN^{-1} phiT; all cross-lane traffic via shuffles, zero barriers.
// wconj stored TRANSPOSED as [n][c][f] so beamform's per-channel reads are
// lane-contiguous.
// ---------------------------------------------------------------------------
__global__ __launch_bounds__(64) void mvdr_weights(
    const float* __restrict__ partial, const int* __restrict__ ref_ptr,
    float2* __restrict__ wconj)
{
    int f = blockIdx.x;
    int n = blockIdx.y;
    int lane = threadIdx.x;

    int r = lane >> 3, c = lane & 7;
    int lo = r < c ? r : c, hi = r < c ? c : r;
    int p = lo * 8 - lo * (lo - 1) / 2 + (hi - lo);

    const float* pT = partial + ((size_t)(0 * Nn + n) * NCHUNK) * SLAB
                      + (size_t)f * 72 + 2 * p;
    const float* pN = partial + ((size_t)(1 * Nn + n) * NCHUNK) * SLAB
                      + (size_t)f * 72 + 2 * p;
    float2 sT = make_float2(0.f, 0.f), sN = make_float2(0.f, 0.f);
#pragma unroll
    for (int ch = 0; ch < NCHUNK; ++ch) {
        float2 vT = *(const float2*)(pT + ch * SLAB);
        float2 vN = *(const float2*)(pN + ch * SLAB);
        sT.x += vT.x; sT.y += vT.y;
        sN.x += vN.x; sN.y += vN.y;
    }

    const float invT = 1.0f / (float)Tt;
    const float dl = 0.001f / 1.41421356237309515f;   // 0.001/sqrt(2)
    float sgn = (r > c) ? -1.f : 1.f;                 // Hermitian reconstruction

    float2 a = make_float2(sN.x * invT, sgn * sN.y * invT);
    float2 b = make_float2(sT.x * invT, sgn * sT.y * invT);
    if (r == c) { a.x += dl; a.y += dl; }             // complex diagonal loading

    for (int k = 0; k < 8; ++k) {
        // --- argmax |A_{jk}|^2 over j >= k (butterfly) ---
        float mag = (c == k && r >= k) ? (a.x * a.x + a.y * a.y) : -1.f;
        int midx = r;
#pragma unroll
        for (int st = 8; st < 64; st <<= 1) {
            float om = __shfl_xor(mag, st, 64);
            int   oi = __shfl_xor(midx, st, 64);
            if (om > mag) { mag = om; midx = oi; }
        }
        int piv = __shfl(midx, k, 64);

        // --- swap rows k <-> piv ---
        int srcr = (r == k) ? piv : ((r == piv) ? k : r);
        int src = srcr * 8 + c;
        a.x = __shfl(a.x, src, 64); a.y = __shfl(a.y, src, 64);
        b.x = __shfl(b.x, src, 64); b.y = __shfl(b.y, src, 64);

        // --- scale row k by 1/pivot ---
        float pvx = __shfl(a.x, k * 8 + k, 64), pvy = __shfl(a.y, k * 8 + k, 64);
        float d = pvx * pvx + pvy * pvy;
        float ipx = pvx / d, ipy = -pvy / d;
        if (r == k) {
            float2 t = a;
            a = make_float2(t.x * ipx - t.y * ipy, t.x * ipy + t.y * ipx);
            t = b;
            b = make_float2(t.x * ipx - t.y * ipy, t.x * ipy + t.y * ipx);
        }

        // --- eliminate all other rows ---
        float rax = __shfl(a.x, k * 8 + c, 64), ray = __shfl(a.y, k * 8 + c, 64);
        float rbx = __shfl(b.x, k * 8 + c, 64), rby = __shfl(b.y, k * 8 + c, 64);
        float fx  = __shfl(a.x, r * 8 + k, 64), fy  = __shfl(a.y, r * 8 + k, 64);
        if (r != k) {
            a.x -= fx * rax - fy * ray;  a.y -= fx * ray + fy * rax;
            b.x -= fx * rbx - fy * rby;  b.y -= fx * rby + fy * rbx;
        }
    }

    // --- l = trace(G): full-wave sum of diagonal entries of B ---
    float tx = (r == c) ? b.x : 0.f, ty = (r == c) ? b.y : 0.f;
#pragma unroll
    for (int st = 1; st < 64; st <<= 1) {
        tx += __shfl_xor(tx, st, 64);
        ty += __shfl_xor(ty, st, 64);
    }

    int ref = *ref_ptr;
    if (c == ref) {                                   // lane (r, ref) holds G_{r,ref}
        float den = tx * tx + ty * ty;
        float wx = (b.x * tx + b.y * ty) / den;       // W = G[:,ref] / l
        float wy = (b.y * tx - b.x * ty) / den;
        // TRANSPOSED layout: [n][c][f]
        wconj[((size_t)n * 8 + r) * Ff + f] = make_float2(wx, -wy);  // conj(W)
    }
}

// ---------------------------------------------------------------------------
// Stage 3: X_bf(n,t,f) = sum_c conj(W)(n,f,c) * y(n,c,t,f)
// wconj layout [n][c][f]: per-channel load is lane-contiguous (512 B/wave).
// ---------------------------------------------------------------------------
__global__ __launch_bounds__(256) void beamform(
    const float* __restrict__ y, const float2* __restrict__ wconj,
    float* __restrict__ out)
{
    int idx = blockIdx.x * 256 + threadIdx.x;   // < N*T*F = 525312
    int n = idx / TFs;
    int rem = idx - n * TFs;
    int t = rem / Ff;
    int f = rem - t * Ff;

    size_t base_re = (size_t)n * 2 * Cc * TFs + (size_t)t * Ff + f;
    size_t base_im = base_re + (size_t)Cc * TFs;
    const float2* w = wconj + (size_t)n * 8 * Ff + f;

    float xr = 0.f, xi = 0.f;
#pragma unroll
    for (int c = 0; c < Cc; ++c) {
        float yre = y[base_re + (size_t)c * TFs];
        float yim = y[base_im + (size_t)c * TFs];
        float2 wc = w[(size_t)c * Ff];
        xr += wc.x * yre - wc.y * yim;
        xi += wc.x * yim + wc.y * yre;
    }
    size_t ob = (size_t)n * 2 * TFs + (size_t)t * Ff + f;
    out[ob] = xr;
    out[ob + TFs] = xi;
}

extern "C" void kernel_launch(void* const* d_in, const int* in_sizes, int n_in,
                              void* d_out, int out_size, void* d_ws, size_t ws_size,
                              hipStream_t stream) {
    const float* mixture = (const float*)d_in[0];
    const float* target  = (const float*)d_in[1];
    const float* noise   = (const float*)d_in[2];
    const int*   refp    = (const int*)d_in[3];
    float* out = (float*)d_out;

    // partial: 2 * Nn * NCHUNK * Ff * 72 floats = ~18.9 MB (ws is ~256 MB)
    float*  partial = (float*)d_ws;
    float2* wconj = (float2*)((char*)d_ws +
                              (size_t)2 * Nn * NCHUNK * SLAB * sizeof(float));

    cov_partial<<<dim3(9, Nn, NCHUNK * 2), 256, 0, stream>>>(target, noise, partial);
    mvdr_weights<<<dim3(Ff, Nn), 64, 0, stream>>>(partial, refp, wconj);
    beamform<<<dim3((Nn * TFs) / 256), 256, 0, stream>>>(mixture, wconj, out);
}